// Round 1
// baseline (287.237 us; speedup 1.0000x reference)
//
#include <hip/hip_runtime.h>
#include <math.h>

// ---------------- workspace layout (float offsets) ----------------
#define WS_OFF_WF   0                       // fused conv1 weights (25*64*10)
#define WS_OFF_B2   16000                   // fused conv1 bias (25)
#define WS_OFF_S1   16032                   // bn1 scale (25)
#define WS_OFF_H1   16064                   // bn1 shift (25)
#define WS_OFF_S2   16096                   // bn2 scale (50)
#define WS_OFF_H2   16160                   // bn2 shift (50)
#define WS_OFF_S3   16224                   // bn3 scale (100)
#define WS_OFF_H3   16352                   // bn3 shift (100)
#define WS_OFF_S4   16480                   // bn4 scale (200)
#define WS_OFF_H4   16704                   // bn4 shift (200)
#define WS_OFF_P1   17024                   // (128,25,247)
#define WS_OFF_P2   (WS_OFF_P1 + 128*25*247)
#define WS_OFF_P3   (WS_OFF_P2 + 128*50*79)
#define WS_OFF_P4   (WS_OFF_P3 + 128*100*23)

__device__ __forceinline__ float eluf(float v) {
    return v > 0.f ? v : (expf(v) - 1.f);
}

// ---------------- K0: precompute fused W, bias2, BN affines ----------------
__global__ __launch_bounds__(256) void k_pre(
    const float* __restrict__ ct_w, const float* __restrict__ ct_b,
    const float* __restrict__ cs_w,
    const float* __restrict__ g1, const float* __restrict__ b1,
    const float* __restrict__ m1, const float* __restrict__ v1,
    const float* __restrict__ g2, const float* __restrict__ b2,
    const float* __restrict__ m2, const float* __restrict__ v2,
    const float* __restrict__ g3, const float* __restrict__ b3,
    const float* __restrict__ m3, const float* __restrict__ v3,
    const float* __restrict__ g4, const float* __restrict__ b4,
    const float* __restrict__ m4, const float* __restrict__ v4,
    float* __restrict__ ws) {
    int t = blockIdx.x * 256 + threadIdx.x;
    if (t < 16000) {
        // Wf[o][c][k] = sum_i cs_w[o,i,c] * ct_w[i,k]
        int o = t / 640, r = t - o * 640, c = r / 10, k = r - c * 10;
        float s = 0.f;
        for (int i = 0; i < 25; ++i)
            s += cs_w[(o * 25 + i) * 64 + c] * ct_w[i * 10 + k];
        ws[WS_OFF_WF + t] = s;
    } else if (t < 16025) {
        int o = t - 16000;
        float s = 0.f;
        for (int i = 0; i < 25; ++i) {
            float cs = 0.f;
            for (int c = 0; c < 64; ++c) cs += cs_w[(o * 25 + i) * 64 + c];
            s += cs * ct_b[i];
        }
        ws[WS_OFF_B2 + o] = s;
    } else if (t >= 16032 && t < 16057) {
        int ch = t - 16032;
        float sc = g1[ch] / sqrtf(v1[ch] + 1e-5f);
        ws[WS_OFF_S1 + ch] = sc;
        ws[WS_OFF_H1 + ch] = b1[ch] - m1[ch] * sc;
    } else if (t >= 16096 && t < 16146) {
        int ch = t - 16096;
        float sc = g2[ch] / sqrtf(v2[ch] + 1e-5f);
        ws[WS_OFF_S2 + ch] = sc;
        ws[WS_OFF_H2 + ch] = b2[ch] - m2[ch] * sc;
    } else if (t >= 16224 && t < 16324) {
        int ch = t - 16224;
        float sc = g3[ch] / sqrtf(v3[ch] + 1e-5f);
        ws[WS_OFF_S3 + ch] = sc;
        ws[WS_OFF_H3 + ch] = b3[ch] - m3[ch] * sc;
    } else if (t >= 16480 && t < 16680) {
        int ch = t - 16480;
        float sc = g4[ch] / sqrtf(v4[ch] + 1e-5f);
        ws[WS_OFF_S4 + ch] = sc;
        ws[WS_OFF_H4 + ch] = b4[ch] - m4[ch] * sc;
    }
}

// ---------------- K1: fused conv1 (64ch,k=10) + BN1 + ELU + pool3 ----------------
// grid (4, B), block 256. tile = 62 pooled outputs.
__global__ __launch_bounds__(256) void k_conv1(
    const float* __restrict__ x, float* __restrict__ ws) {
    const float* Wf  = ws + WS_OFF_WF;
    const float* bb2 = ws + WS_OFF_B2;
    const float* sv  = ws + WS_OFF_S1;
    const float* hv  = ws + WS_OFF_H1;
    float* p1 = ws + WS_OFF_P1;

    int b   = blockIdx.y;
    int tp0 = blockIdx.x * 62;
    int ntp = min(62, 247 - tp0);
    int L   = 3 * ntp + 9;                       // <= 195
    __shared__ float xs[64][200];
    const float* xb = x + (size_t)b * 64 * 750 + 3 * tp0;
    for (int c = 0; c < 64; ++c)
        for (int tl = threadIdx.x; tl < 200; tl += 256)
            xs[c][tl] = (tl < L) ? xb[c * 750 + tl] : 0.f;
    __syncthreads();

    for (int i = threadIdx.x; i < 25 * 31; i += 256) {
        int o = i / 31, pl = i - o * 31;
        int tp = 2 * pl;
        if (tp >= ntp) continue;
        bool two = (tp + 1 < ntp);
        const float* Wo = Wf + o * 640;
        float a0 = 0, a1 = 0, a2 = 0, a3 = 0, a4 = 0, a5 = 0;
        int base = 3 * tp;
        for (int c = 0; c < 64; ++c) {
            float xv[15];
#pragma unroll
            for (int j = 0; j < 15; ++j) xv[j] = xs[c][base + j];
            const float* wr = Wo + c * 10;
#pragma unroll
            for (int k = 0; k < 10; ++k) {
                float w = wr[k];
                a0 += w * xv[k];     a1 += w * xv[k + 1]; a2 += w * xv[k + 2];
                a3 += w * xv[k + 3]; a4 += w * xv[k + 4]; a5 += w * xv[k + 5];
            }
        }
        float s = sv[o], hh = hv[o], bo = bb2[o];
        float y0 = eluf((a0 + bo) * s + hh);
        float y1 = eluf((a1 + bo) * s + hh);
        float y2 = eluf((a2 + bo) * s + hh);
        p1[((size_t)b * 25 + o) * 247 + tp0 + tp] = fmaxf(fmaxf(y0, y1), y2);
        if (two) {
            float z0 = eluf((a3 + bo) * s + hh);
            float z1 = eluf((a4 + bo) * s + hh);
            float z2 = eluf((a5 + bo) * s + hh);
            p1[((size_t)b * 25 + o) * 247 + tp0 + tp + 1] = fmaxf(fmaxf(z0, z1), z2);
        }
    }
}

// ---------------- K2: conv2 (25->50,k=10) + BN2 + ELU + pool3 ----------------
// grid (2, B), block 256. tp tiles of 40 (40 + 39 = 79).
__global__ __launch_bounds__(256) void k_conv2(
    float* __restrict__ ws, const float* __restrict__ w2) {
    const float* p1 = ws + WS_OFF_P1;
    const float* sv = ws + WS_OFF_S2;
    const float* hv = ws + WS_OFF_H2;
    float* p2 = ws + WS_OFF_P2;

    int b   = blockIdx.y;
    int tp0 = blockIdx.x * 40;
    int ntp = min(40, 79 - tp0);
    int L   = 3 * ntp + 9;                        // <= 129
    __shared__ float ys[25][132];
    for (int r = 0; r < 25; ++r)
        for (int tl = threadIdx.x; tl < 132; tl += 256)
            ys[r][tl] = (tl < L) ? p1[((size_t)b * 25 + r) * 247 + 3 * tp0 + tl] : 0.f;
    __syncthreads();

    for (int i = threadIdx.x; i < 50 * 20; i += 256) {
        int o = i / 20, pl = i - o * 20;
        int tp = 2 * pl;
        if (tp >= ntp) continue;
        bool two = (tp + 1 < ntp);
        float a0 = 0, a1 = 0, a2 = 0, a3 = 0, a4 = 0, a5 = 0;
        int base = 3 * tp;
        for (int ci = 0; ci < 25; ++ci) {
            float xv[15];
#pragma unroll
            for (int j = 0; j < 15; ++j) xv[j] = ys[ci][base + j];
            const float* wr = w2 + (o * 25 + ci) * 10;
#pragma unroll
            for (int k = 0; k < 10; ++k) {
                float w = wr[k];
                a0 += w * xv[k];     a1 += w * xv[k + 1]; a2 += w * xv[k + 2];
                a3 += w * xv[k + 3]; a4 += w * xv[k + 4]; a5 += w * xv[k + 5];
            }
        }
        float s = sv[o], hh = hv[o];
        float m0 = fmaxf(fmaxf(eluf(a0 * s + hh), eluf(a1 * s + hh)), eluf(a2 * s + hh));
        p2[((size_t)b * 50 + o) * 79 + tp0 + tp] = m0;
        if (two) {
            float m1 = fmaxf(fmaxf(eluf(a3 * s + hh), eluf(a4 * s + hh)), eluf(a5 * s + hh));
            p2[((size_t)b * 50 + o) * 79 + tp0 + tp + 1] = m1;
        }
    }
}

// ---------------- K3: conv3 (50->100,k=10) + BN3 + ELU + pool3 ----------------
// grid (2, B) split over output channels (50 each), block 256.
__global__ __launch_bounds__(256) void k_conv3(
    float* __restrict__ ws, const float* __restrict__ w3) {
    const float* p2 = ws + WS_OFF_P2;
    const float* sv = ws + WS_OFF_S3;
    const float* hv = ws + WS_OFF_H3;
    float* p3 = ws + WS_OFF_P3;

    int b  = blockIdx.y;
    int oh = blockIdx.x * 50;
    __shared__ float ys[50][84];
    for (int r = 0; r < 50; ++r)
        for (int tl = threadIdx.x; tl < 84; tl += 256)
            ys[r][tl] = (tl < 79) ? p2[((size_t)b * 50 + r) * 79 + tl] : 0.f;
    __syncthreads();

    for (int i = threadIdx.x; i < 50 * 12; i += 256) {
        int ol = i / 12, pl = i - ol * 12;
        int o = oh + ol;
        int tp = 2 * pl;
        bool two = (tp + 1 < 23);
        float a0 = 0, a1 = 0, a2 = 0, a3 = 0, a4 = 0, a5 = 0;
        int base = 3 * tp;                        // <= 66, +14 = 80 < 84
        for (int ci = 0; ci < 50; ++ci) {
            float xv[15];
#pragma unroll
            for (int j = 0; j < 15; ++j) xv[j] = ys[ci][base + j];
            const float* wr = w3 + (o * 50 + ci) * 10;
#pragma unroll
            for (int k = 0; k < 10; ++k) {
                float w = wr[k];
                a0 += w * xv[k];     a1 += w * xv[k + 1]; a2 += w * xv[k + 2];
                a3 += w * xv[k + 3]; a4 += w * xv[k + 4]; a5 += w * xv[k + 5];
            }
        }
        float s = sv[o], hh = hv[o];
        float m0 = fmaxf(fmaxf(eluf(a0 * s + hh), eluf(a1 * s + hh)), eluf(a2 * s + hh));
        p3[((size_t)b * 100 + o) * 23 + tp] = m0;
        if (two) {
            float m1 = fmaxf(fmaxf(eluf(a3 * s + hh), eluf(a4 * s + hh)), eluf(a5 * s + hh));
            p3[((size_t)b * 100 + o) * 23 + tp + 1] = m1;
        }
    }
}

// ---------------- K4: conv4 (100->200,k=10) + BN4 + ELU + pool3 ----------------
// grid (2, B) split over output channels (100 each), block 256.
__global__ __launch_bounds__(256) void k_conv4(
    float* __restrict__ ws, const float* __restrict__ w4) {
    const float* p3 = ws + WS_OFF_P3;
    const float* sv = ws + WS_OFF_S4;
    const float* hv = ws + WS_OFF_H4;
    float* p4 = ws + WS_OFF_P4;

    int b  = blockIdx.y;
    int oh = blockIdx.x * 100;
    __shared__ float ys[100][24];
    for (int r = 0; r < 100; ++r)
        for (int tl = threadIdx.x; tl < 24; tl += 256)
            ys[r][tl] = (tl < 23) ? p3[((size_t)b * 100 + r) * 23 + tl] : 0.f;
    __syncthreads();

    for (int i = threadIdx.x; i < 100 * 2; i += 256) {
        int ol = i / 2, pl = i - ol * 2;
        int o = oh + ol;
        int tp = 2 * pl;                          // 0 or 2; both tp,tp+1 valid
        float a0 = 0, a1 = 0, a2 = 0, a3 = 0, a4 = 0, a5 = 0;
        int base = 3 * tp;                        // 0 or 6, +14 = 20 < 24
        for (int ci = 0; ci < 100; ++ci) {
            float xv[15];
#pragma unroll
            for (int j = 0; j < 15; ++j) xv[j] = ys[ci][base + j];
            const float* wr = w4 + (o * 100 + ci) * 10;
#pragma unroll
            for (int k = 0; k < 10; ++k) {
                float w = wr[k];
                a0 += w * xv[k];     a1 += w * xv[k + 1]; a2 += w * xv[k + 2];
                a3 += w * xv[k + 3]; a4 += w * xv[k + 4]; a5 += w * xv[k + 5];
            }
        }
        float s = sv[o], hh = hv[o];
        float m0 = fmaxf(fmaxf(eluf(a0 * s + hh), eluf(a1 * s + hh)), eluf(a2 * s + hh));
        p4[((size_t)b * 200 + o) * 4 + tp] = m0;
        float m1 = fmaxf(fmaxf(eluf(a3 * s + hh), eluf(a4 * s + hh)), eluf(a5 * s + hh));
        p4[((size_t)b * 200 + o) * 4 + tp + 1] = m1;
    }
}

// ---------------- K5: fc conv + per-sample MoE heads ----------------
// grid (B), block 128 (= HID).
__global__ __launch_bounds__(128) void k_heads(
    const float* __restrict__ ws,
    const float* __restrict__ fcw, const float* __restrict__ fcb,
    const int* __restrict__ cids,
    const float* __restrict__ hW1, const float* __restrict__ hb1,
    const float* __restrict__ hW2, const float* __restrict__ hb2,
    float* __restrict__ out) {
    const float* p4 = ws + WS_OFF_P4;
    __shared__ float red[4][128];
    __shared__ float fs[4];
    int b = blockIdx.x, j = threadIdx.x;

    float pa[4] = {0.f, 0.f, 0.f, 0.f};
    for (int c = j; c < 200; c += 128) {
        const float* pp = p4 + ((size_t)b * 200 + c) * 4;
        float v0 = pp[0], v1 = pp[1], v2 = pp[2], v3 = pp[3];
#pragma unroll
        for (int o = 0; o < 4; ++o) {
            const float* fw = fcw + (o * 200 + c) * 4;
            pa[o] += fw[0] * v0 + fw[1] * v1 + fw[2] * v2 + fw[3] * v3;
        }
    }
#pragma unroll
    for (int o = 0; o < 4; ++o) red[o][j] = pa[o];
    __syncthreads();
    for (int s = 64; s > 0; s >>= 1) {
        if (j < s) {
#pragma unroll
            for (int o = 0; o < 4; ++o) red[o][j] += red[o][j + s];
        }
        __syncthreads();
    }
    if (j < 4) fs[j] = red[j][0] + fcb[j];
    __syncthreads();

    int cid = cids[b];
    float hvv = hb1[cid * 128 + j];
#pragma unroll
    for (int f = 0; f < 4; ++f) hvv += fs[f] * hW1[(cid * 4 + f) * 128 + j];
    hvv = fmaxf(hvv, 0.f);
#pragma unroll
    for (int o = 0; o < 4; ++o) red[o][j] = hvv * hW2[(cid * 128 + j) * 4 + o];
    __syncthreads();
    for (int s = 64; s > 0; s >>= 1) {
        if (j < s) {
#pragma unroll
            for (int o = 0; o < 4; ++o) red[o][j] += red[o][j + s];
        }
        __syncthreads();
    }
    if (j < 4) out[b * 4 + j] = red[j][0] + hb2[cid * 4 + j];
}

// ---------------- launch ----------------
extern "C" void kernel_launch(void* const* d_in, const int* in_sizes, int n_in,
                              void* d_out, int out_size, void* d_ws, size_t ws_size,
                              hipStream_t stream) {
    (void)in_sizes; (void)n_in; (void)out_size; (void)ws_size;
    const float* x    = (const float*)d_in[0];
    const int*   cid  = (const int*)d_in[1];
    const float* ctw  = (const float*)d_in[2];
    const float* ctb  = (const float*)d_in[3];
    const float* csw  = (const float*)d_in[4];
    const float* g1 = (const float*)d_in[5],  *b1 = (const float*)d_in[6];
    const float* m1 = (const float*)d_in[7],  *v1 = (const float*)d_in[8];
    const float* w2 = (const float*)d_in[9];
    const float* g2 = (const float*)d_in[10], *b2 = (const float*)d_in[11];
    const float* m2 = (const float*)d_in[12], *v2 = (const float*)d_in[13];
    const float* w3 = (const float*)d_in[14];
    const float* g3 = (const float*)d_in[15], *b3 = (const float*)d_in[16];
    const float* m3 = (const float*)d_in[17], *v3 = (const float*)d_in[18];
    const float* w4 = (const float*)d_in[19];
    const float* g4 = (const float*)d_in[20], *b4 = (const float*)d_in[21];
    const float* m4 = (const float*)d_in[22], *v4 = (const float*)d_in[23];
    const float* fcw = (const float*)d_in[24], *fcb = (const float*)d_in[25];
    const float* hW1 = (const float*)d_in[26], *hb1 = (const float*)d_in[27];
    const float* hW2 = (const float*)d_in[28], *hb2 = (const float*)d_in[29];
    float* ws  = (float*)d_ws;
    float* out = (float*)d_out;

    k_pre<<<dim3(66), dim3(256), 0, stream>>>(ctw, ctb, csw,
        g1, b1, m1, v1, g2, b2, m2, v2, g3, b3, m3, v3, g4, b4, m4, v4, ws);
    k_conv1<<<dim3(4, 128), dim3(256), 0, stream>>>(x, ws);
    k_conv2<<<dim3(2, 128), dim3(256), 0, stream>>>(ws, w2);
    k_conv3<<<dim3(2, 128), dim3(256), 0, stream>>>(ws, w3);
    k_conv4<<<dim3(2, 128), dim3(256), 0, stream>>>(ws, w4);
    k_heads<<<dim3(128), dim3(128), 0, stream>>>(ws, fcw, fcb, cid,
                                                 hW1, hb1, hW2, hb2, out);
}

// Round 2
// 198.682 us; speedup vs baseline: 1.4457x; 1.4457x over previous
//
#include <hip/hip_runtime.h>
#include <math.h>

// ---------------- workspace layout (float offsets) ----------------
#define WS_OFF_WF   0                       // fused conv1 weights (25*64*10)
#define WS_OFF_B2   16000                   // fused conv1 bias (25)
#define WS_OFF_S1   16032                   // bn1 scale (25)
#define WS_OFF_H1   16064                   // bn1 shift (25)
#define WS_OFF_S2   16096                   // bn2 scale (50)
#define WS_OFF_H2   16160                   // bn2 shift (50)
#define WS_OFF_S3   16224                   // bn3 scale (100)
#define WS_OFF_H3   16352                   // bn3 shift (100)
#define WS_OFF_S4   16480                   // bn4 scale (200)
#define WS_OFF_H4   16704                   // bn4 shift (200)
#define WS_OFF_P1   17024                   // (128,25,247)
#define WS_OFF_P2   (WS_OFF_P1 + 128*25*247)
#define WS_OFF_P3   (WS_OFF_P2 + 128*50*79)
#define WS_OFF_P4   (WS_OFF_P3 + 128*100*23)

__device__ __forceinline__ float eluf(float v) {
    return v > 0.f ? v : (expf(v) - 1.f);
}

// ---------------- K0: precompute fused W, bias2, BN affines ----------------
__global__ __launch_bounds__(256) void k_pre(
    const float* __restrict__ ct_w, const float* __restrict__ ct_b,
    const float* __restrict__ cs_w,
    const float* __restrict__ g1, const float* __restrict__ b1,
    const float* __restrict__ m1, const float* __restrict__ v1,
    const float* __restrict__ g2, const float* __restrict__ b2,
    const float* __restrict__ m2, const float* __restrict__ v2,
    const float* __restrict__ g3, const float* __restrict__ b3,
    const float* __restrict__ m3, const float* __restrict__ v3,
    const float* __restrict__ g4, const float* __restrict__ b4,
    const float* __restrict__ m4, const float* __restrict__ v4,
    float* __restrict__ ws) {
    int t = blockIdx.x * 256 + threadIdx.x;
    if (t < 16000) {
        int o = t / 640, r = t - o * 640, c = r / 10, k = r - c * 10;
        float s = 0.f;
        for (int i = 0; i < 25; ++i)
            s += cs_w[(o * 25 + i) * 64 + c] * ct_w[i * 10 + k];
        ws[WS_OFF_WF + t] = s;
    } else if (t < 16025) {
        int o = t - 16000;
        float s = 0.f;
        for (int i = 0; i < 25; ++i) {
            float cs = 0.f;
            for (int c = 0; c < 64; ++c) cs += cs_w[(o * 25 + i) * 64 + c];
            s += cs * ct_b[i];
        }
        ws[WS_OFF_B2 + o] = s;
    } else if (t >= 16032 && t < 16057) {
        int ch = t - 16032;
        float sc = g1[ch] / sqrtf(v1[ch] + 1e-5f);
        ws[WS_OFF_S1 + ch] = sc;
        ws[WS_OFF_H1 + ch] = b1[ch] - m1[ch] * sc;
    } else if (t >= 16096 && t < 16146) {
        int ch = t - 16096;
        float sc = g2[ch] / sqrtf(v2[ch] + 1e-5f);
        ws[WS_OFF_S2 + ch] = sc;
        ws[WS_OFF_H2 + ch] = b2[ch] - m2[ch] * sc;
    } else if (t >= 16224 && t < 16324) {
        int ch = t - 16224;
        float sc = g3[ch] / sqrtf(v3[ch] + 1e-5f);
        ws[WS_OFF_S3 + ch] = sc;
        ws[WS_OFF_H3 + ch] = b3[ch] - m3[ch] * sc;
    } else if (t >= 16480 && t < 16680) {
        int ch = t - 16480;
        float sc = g4[ch] / sqrtf(v4[ch] + 1e-5f);
        ws[WS_OFF_S4 + ch] = sc;
        ws[WS_OFF_H4 + ch] = b4[ch] - m4[ch] * sc;
    }
}

// ---------------- K1: fused conv1 + BN1 + ELU + pool3 ----------------
// grid (7, B), block 256. tile = 40 pooled outputs, 4 pooled per thread.
// work items = 25 o * 10 quads = 250.
__global__ __launch_bounds__(256) void k_conv1(
    const float* __restrict__ x, float* __restrict__ ws) {
    int b = blockIdx.y, bx = blockIdx.x;
    int tp0 = bx * 40;
    int ntp = min(40, 247 - tp0);
    __shared__ float xs[64][132];                 // 132 floats = 528 B (16B mult)
    const float* xb = x + (size_t)b * 48000 + 3 * tp0;
    if (ntp == 40) {
        // full tile: 3*tp0+131 <= 731 < 750, all in-bounds. float2 staging
        // (words offset 750c + 120bx is even -> 8B aligned).
        for (int idx = threadIdx.x; idx < 64 * 66; idx += 256) {
            int c = idx / 66, j = idx - c * 66;
            *(float2*)&xs[c][2 * j] = *(const float2*)(xb + c * 750 + 2 * j);
        }
    } else {
        for (int idx = threadIdx.x; idx < 64 * 132; idx += 256) {
            int c = idx / 132, tl = idx - c * 132;
            xs[c][tl] = (3 * tp0 + tl < 750) ? xb[c * 750 + tl] : 0.f;
        }
    }
    __syncthreads();

    int i = threadIdx.x;
    if (i >= 250) return;
    int o = i / 10, q = i - o * 10;
    int tpb = tp0 + 4 * q;
    int tpe = tp0 + ntp;
    if (tpb >= tpe) return;
    const float* Wo = ws + WS_OFF_WF + o * 640;
    float acc[12];
#pragma unroll
    for (int r = 0; r < 12; ++r) acc[r] = 0.f;

    for (int c = 0; c < 64; ++c) {
        const float4* xp = (const float4*)&xs[c][12 * q];   // 48q B: 16B aligned
        float xv[24];
#pragma unroll
        for (int j = 0; j < 6; ++j) {
            float4 t = xp[j];
            xv[4 * j] = t.x; xv[4 * j + 1] = t.y; xv[4 * j + 2] = t.z; xv[4 * j + 3] = t.w;
        }
        const float2* wp = (const float2*)(Wo + c * 10);    // 8B aligned
        float w[10];
#pragma unroll
        for (int j = 0; j < 5; ++j) { float2 t = wp[j]; w[2 * j] = t.x; w[2 * j + 1] = t.y; }
#pragma unroll
        for (int k = 0; k < 10; ++k)
#pragma unroll
            for (int r = 0; r < 12; ++r) acc[r] += w[k] * xv[k + r];
    }

    float s = ws[WS_OFF_S1 + o], hh = ws[WS_OFF_H1 + o], bo = ws[WS_OFF_B2 + o];
    float* p1 = ws + WS_OFF_P1 + ((size_t)b * 25 + o) * 247;
#pragma unroll
    for (int m = 0; m < 4; ++m) {
        int tp = tpb + m;
        if (tp < tpe) {
            float y0 = eluf((acc[3 * m] + bo) * s + hh);
            float y1 = eluf((acc[3 * m + 1] + bo) * s + hh);
            float y2 = eluf((acc[3 * m + 2] + bo) * s + hh);
            p1[tp] = fmaxf(fmaxf(y0, y1), y2);
        }
    }
}

// ---------------- K2: conv2 (25->50) + BN2 + ELU + pool3 ----------------
// grid (4, B), block 256. tile = 20 pooled, 4 per thread. items = 50*5 = 250.
__global__ __launch_bounds__(256) void k_conv2(
    float* __restrict__ ws, const float* __restrict__ w2) {
    const float* p1 = ws + WS_OFF_P1;
    float* p2 = ws + WS_OFF_P2;
    int b = blockIdx.y, bx = blockIdx.x;
    int tp0 = bx * 20;
    int ntp = min(20, 79 - tp0);
    __shared__ float ys[25][72];                  // 288 B rows (16B mult)
    for (int idx = threadIdx.x; idx < 25 * 72; idx += 256) {
        int r = idx / 72, tl = idx - r * 72;
        int g = 3 * tp0 + tl;
        ys[r][tl] = (g < 247) ? p1[((size_t)b * 25 + r) * 247 + g] : 0.f;
    }
    __syncthreads();

    int i = threadIdx.x;
    if (i >= 250) return;
    int o = i / 5, q = i - o * 5;
    int tpb = tp0 + 4 * q;
    int tpe = tp0 + ntp;
    if (tpb >= tpe) return;
    float acc[12];
#pragma unroll
    for (int r = 0; r < 12; ++r) acc[r] = 0.f;

    for (int c = 0; c < 25; ++c) {
        const float4* xp = (const float4*)&ys[c][12 * q];
        float xv[24];
#pragma unroll
        for (int j = 0; j < 6; ++j) {
            float4 t = xp[j];
            xv[4 * j] = t.x; xv[4 * j + 1] = t.y; xv[4 * j + 2] = t.z; xv[4 * j + 3] = t.w;
        }
        const float2* wp = (const float2*)(w2 + (o * 25 + c) * 10);
        float w[10];
#pragma unroll
        for (int j = 0; j < 5; ++j) { float2 t = wp[j]; w[2 * j] = t.x; w[2 * j + 1] = t.y; }
#pragma unroll
        for (int k = 0; k < 10; ++k)
#pragma unroll
            for (int r = 0; r < 12; ++r) acc[r] += w[k] * xv[k + r];
    }

    float s = ws[WS_OFF_S2 + o], hh = ws[WS_OFF_H2 + o];
    float* po = p2 + ((size_t)b * 50 + o) * 79;
#pragma unroll
    for (int m = 0; m < 4; ++m) {
        int tp = tpb + m;
        if (tp < tpe) {
            float y0 = eluf(acc[3 * m] * s + hh);
            float y1 = eluf(acc[3 * m + 1] * s + hh);
            float y2 = eluf(acc[3 * m + 2] * s + hh);
            po[tp] = fmaxf(fmaxf(y0, y1), y2);
        }
    }
}

// ---------------- K3: conv3 (50->100) + BN3 + ELU + pool3 ----------------
// grid (4, B), block 192. o-split: 25 o per block, 6 quads. items = 150.
__global__ __launch_bounds__(192) void k_conv3(
    float* __restrict__ ws, const float* __restrict__ w3) {
    const float* p2 = ws + WS_OFF_P2;
    float* p3 = ws + WS_OFF_P3;
    int b = blockIdx.y;
    int o0 = blockIdx.x * 25;
    __shared__ float ys[50][84];                  // 336 B rows (16B mult)
    for (int idx = threadIdx.x; idx < 50 * 84; idx += 192) {
        int r = idx / 84, tl = idx - r * 84;
        ys[r][tl] = (tl < 79) ? p2[((size_t)b * 50 + r) * 79 + tl] : 0.f;
    }
    __syncthreads();

    int i = threadIdx.x;
    if (i >= 150) return;
    int ol = i / 6, q = i - ol * 6;
    int o = o0 + ol;
    float acc[12];
#pragma unroll
    for (int r = 0; r < 12; ++r) acc[r] = 0.f;

    for (int c = 0; c < 50; ++c) {
        const float4* xp = (const float4*)&ys[c][12 * q];
        float xv[24];
#pragma unroll
        for (int j = 0; j < 6; ++j) {
            float4 t = xp[j];
            xv[4 * j] = t.x; xv[4 * j + 1] = t.y; xv[4 * j + 2] = t.z; xv[4 * j + 3] = t.w;
        }
        const float2* wp = (const float2*)(w3 + (o * 50 + c) * 10);
        float w[10];
#pragma unroll
        for (int j = 0; j < 5; ++j) { float2 t = wp[j]; w[2 * j] = t.x; w[2 * j + 1] = t.y; }
#pragma unroll
        for (int k = 0; k < 10; ++k)
#pragma unroll
            for (int r = 0; r < 12; ++r) acc[r] += w[k] * xv[k + r];
    }

    float s = ws[WS_OFF_S3 + o], hh = ws[WS_OFF_H3 + o];
    float* po = p3 + ((size_t)b * 100 + o) * 23;
#pragma unroll
    for (int m = 0; m < 4; ++m) {
        int tp = 4 * q + m;
        if (tp < 23) {
            float y0 = eluf(acc[3 * m] * s + hh);
            float y1 = eluf(acc[3 * m + 1] * s + hh);
            float y2 = eluf(acc[3 * m + 2] * s + hh);
            po[tp] = fmaxf(fmaxf(y0, y1), y2);
        }
    }
}

// ---------------- K4: conv4 (100->200) + BN4 + ELU + pool3 ----------------
// grid (2, B), block 256. pair-split: pooled {2*bx, 2*bx+1}. items = 200 o.
__global__ __launch_bounds__(256) void k_conv4(
    float* __restrict__ ws, const float* __restrict__ w4) {
    const float* p3 = ws + WS_OFF_P3;
    float* p4 = ws + WS_OFF_P4;
    int b = blockIdx.y, pr = blockIdx.x;
    __shared__ float ys[100][24];                 // 96 B rows (16B mult)
    for (int idx = threadIdx.x; idx < 100 * 24; idx += 256) {
        int r = idx / 24, tl = idx - r * 24;
        ys[r][tl] = (tl < 23) ? p3[((size_t)b * 100 + r) * 23 + tl] : 0.f;
    }
    __syncthreads();

    int o = threadIdx.x;
    if (o >= 200) return;
    float acc[6];
#pragma unroll
    for (int r = 0; r < 6; ++r) acc[r] = 0.f;

    for (int c = 0; c < 100; ++c) {
        const float2* xp = (const float2*)&ys[c][6 * pr];   // 24B*pr: 8B aligned
        float xv[16];
#pragma unroll
        for (int j = 0; j < 8; ++j) { float2 t = xp[j]; xv[2 * j] = t.x; xv[2 * j + 1] = t.y; }
        const float2* wp = (const float2*)(w4 + (o * 100 + c) * 10);
        float w[10];
#pragma unroll
        for (int j = 0; j < 5; ++j) { float2 t = wp[j]; w[2 * j] = t.x; w[2 * j + 1] = t.y; }
#pragma unroll
        for (int k = 0; k < 10; ++k)
#pragma unroll
            for (int r = 0; r < 6; ++r) acc[r] += w[k] * xv[k + r];
    }

    float s = ws[WS_OFF_S4 + o], hh = ws[WS_OFF_H4 + o];
    float* po = p4 + ((size_t)b * 200 + o) * 4 + 2 * pr;
#pragma unroll
    for (int m = 0; m < 2; ++m) {
        float y0 = eluf(acc[3 * m] * s + hh);
        float y1 = eluf(acc[3 * m + 1] * s + hh);
        float y2 = eluf(acc[3 * m + 2] * s + hh);
        po[m] = fmaxf(fmaxf(y0, y1), y2);
    }
}

// ---------------- K5: fc conv + per-sample MoE heads ----------------
__global__ __launch_bounds__(128) void k_heads(
    const float* __restrict__ ws,
    const float* __restrict__ fcw, const float* __restrict__ fcb,
    const int* __restrict__ cids,
    const float* __restrict__ hW1, const float* __restrict__ hb1,
    const float* __restrict__ hW2, const float* __restrict__ hb2,
    float* __restrict__ out) {
    const float* p4 = ws + WS_OFF_P4;
    __shared__ float red[4][128];
    __shared__ float fs[4];
    int b = blockIdx.x, j = threadIdx.x;

    float pa[4] = {0.f, 0.f, 0.f, 0.f};
    for (int c = j; c < 200; c += 128) {
        const float* pp = p4 + ((size_t)b * 200 + c) * 4;
        float v0 = pp[0], v1 = pp[1], v2 = pp[2], v3 = pp[3];
#pragma unroll
        for (int o = 0; o < 4; ++o) {
            const float* fw = fcw + (o * 200 + c) * 4;
            pa[o] += fw[0] * v0 + fw[1] * v1 + fw[2] * v2 + fw[3] * v3;
        }
    }
#pragma unroll
    for (int o = 0; o < 4; ++o) red[o][j] = pa[o];
    __syncthreads();
    for (int s = 64; s > 0; s >>= 1) {
        if (j < s) {
#pragma unroll
            for (int o = 0; o < 4; ++o) red[o][j] += red[o][j + s];
        }
        __syncthreads();
    }
    if (j < 4) fs[j] = red[j][0] + fcb[j];
    __syncthreads();

    int cid = cids[b];
    float hvv = hb1[cid * 128 + j];
#pragma unroll
    for (int f = 0; f < 4; ++f) hvv += fs[f] * hW1[(cid * 4 + f) * 128 + j];
    hvv = fmaxf(hvv, 0.f);
#pragma unroll
    for (int o = 0; o < 4; ++o) red[o][j] = hvv * hW2[(cid * 128 + j) * 4 + o];
    __syncthreads();
    for (int s = 64; s > 0; s >>= 1) {
        if (j < s) {
#pragma unroll
            for (int o = 0; o < 4; ++o) red[o][j] += red[o][j + s];
        }
        __syncthreads();
    }
    if (j < 4) out[b * 4 + j] = red[j][0] + hb2[cid * 4 + j];
}

// ---------------- launch ----------------
extern "C" void kernel_launch(void* const* d_in, const int* in_sizes, int n_in,
                              void* d_out, int out_size, void* d_ws, size_t ws_size,
                              hipStream_t stream) {
    (void)in_sizes; (void)n_in; (void)out_size; (void)ws_size;
    const float* x    = (const float*)d_in[0];
    const int*   cid  = (const int*)d_in[1];
    const float* ctw  = (const float*)d_in[2];
    const float* ctb  = (const float*)d_in[3];
    const float* csw  = (const float*)d_in[4];
    const float* g1 = (const float*)d_in[5],  *b1 = (const float*)d_in[6];
    const float* m1 = (const float*)d_in[7],  *v1 = (const float*)d_in[8];
    const float* w2 = (const float*)d_in[9];
    const float* g2 = (const float*)d_in[10], *b2 = (const float*)d_in[11];
    const float* m2 = (const float*)d_in[12], *v2 = (const float*)d_in[13];
    const float* w3 = (const float*)d_in[14];
    const float* g3 = (const float*)d_in[15], *b3 = (const float*)d_in[16];
    const float* m3 = (const float*)d_in[17], *v3 = (const float*)d_in[18];
    const float* w4 = (const float*)d_in[19];
    const float* g4 = (const float*)d_in[20], *b4 = (const float*)d_in[21];
    const float* m4 = (const float*)d_in[22], *v4 = (const float*)d_in[23];
    const float* fcw = (const float*)d_in[24], *fcb = (const float*)d_in[25];
    const float* hW1 = (const float*)d_in[26], *hb1 = (const float*)d_in[27];
    const float* hW2 = (const float*)d_in[28], *hb2 = (const float*)d_in[29];
    float* ws  = (float*)d_ws;
    float* out = (float*)d_out;

    k_pre<<<dim3(66), dim3(256), 0, stream>>>(ctw, ctb, csw,
        g1, b1, m1, v1, g2, b2, m2, v2, g3, b3, m3, v3, g4, b4, m4, v4, ws);
    k_conv1<<<dim3(7, 128), dim3(256), 0, stream>>>(x, ws);
    k_conv2<<<dim3(4, 128), dim3(256), 0, stream>>>(ws, w2);
    k_conv3<<<dim3(4, 128), dim3(192), 0, stream>>>(ws, w3);
    k_conv4<<<dim3(2, 128), dim3(256), 0, stream>>>(ws, w4);
    k_heads<<<dim3(128), dim3(128), 0, stream>>>(ws, fcw, fcb, cid,
                                                 hW1, hb1, hW2, hb2, out);
}

// Round 3
// 166.169 us; speedup vs baseline: 1.7286x; 1.1957x over previous
//
#include <hip/hip_runtime.h>
#include <hip/hip_bf16.h>
#include <math.h>

typedef __attribute__((ext_vector_type(8))) short short8v;
typedef __attribute__((ext_vector_type(4))) float f32x4;

// ---------------- ws layout ----------------
// float region (offsets in floats from ws base):
#define F_S1 0
#define F_H1 32
#define F_S2 64
#define F_H2 128
#define F_S3 192
#define F_H3 320
#define F_S4 448
#define F_H4 704
#define F_B1 960
#define F_P4 1024                       // 128*200*4 floats
#define F_END (1024 + 128*200*4)
// bf16 region (offsets in bf16 units from ws base):
#define H_BASE (F_END * 2)
#define H_P1  H_BASE                    // 128*25*247
#define H_P2  (H_P1 + 128*25*247)       // 128*50*79
#define H_P3  (H_P2 + 128*50*79)        // 128*100*23
#define H_WA1 (H_P3 + 128*100*23)       // 32*640   (o, kk*64+c)
#define H_WA2 (H_WA1 + 32*640)          // 64*320   (o, kk*32+c)
#define H_WA3 (H_WA2 + 64*320)          // 112*640  (o, kk*64+c)
#define H_WA4 (H_WA3 + 112*640)         // 208*1280 (o, kk*128+c)

__device__ __forceinline__ float eluf(float v) {
    return v > 0.f ? v : (expf(v) - 1.f);
}
__device__ __forceinline__ float ldf(const float* p) { return *p; }
__device__ __forceinline__ float ldf(const __hip_bfloat16* p) { return __bfloat162float(*p); }
__device__ __forceinline__ void stf(float* p, float v) { *p = v; }
__device__ __forceinline__ void stf(__hip_bfloat16* p, float v) { *p = __float2bfloat16(v); }

// ---------------- K0: precompute bf16 k-major weights + BN affines ----------------
#define N_WA1 (32*640)
#define N_WA2 (64*320)
#define N_WA3 (112*640)
#define N_WA4 (208*1280)
#define N_WTOT (N_WA1 + N_WA2 + N_WA3 + N_WA4)

__global__ __launch_bounds__(256) void k_pre2(
    const float* __restrict__ ct_w, const float* __restrict__ ct_b,
    const float* __restrict__ cs_w,
    const float* __restrict__ g1, const float* __restrict__ b1,
    const float* __restrict__ m1, const float* __restrict__ v1,
    const float* __restrict__ w2,
    const float* __restrict__ g2, const float* __restrict__ b2,
    const float* __restrict__ m2, const float* __restrict__ v2,
    const float* __restrict__ w3,
    const float* __restrict__ g3, const float* __restrict__ b3,
    const float* __restrict__ m3, const float* __restrict__ v3,
    const float* __restrict__ w4,
    const float* __restrict__ g4, const float* __restrict__ b4,
    const float* __restrict__ m4, const float* __restrict__ v4,
    float* __restrict__ ws) {
    __hip_bfloat16* wsh = (__hip_bfloat16*)ws;
    int t = blockIdx.x * 256 + threadIdx.x;
    if (t < N_WA1) {
        // fused conv1 weight: Wf[o][c][kk] = sum_i cs_w[o,i,c]*ct_w[i,kk], k-major (kk*64+c)
        int o = t / 640, kv = t - o * 640, kk = kv / 64, c = kv - kk * 64;
        float s = 0.f;
        if (o < 25)
            for (int i = 0; i < 25; ++i)
                s += cs_w[(o * 25 + i) * 64 + c] * ct_w[i * 10 + kk];
        wsh[H_WA1 + t] = __float2bfloat16(s);
    } else if (t < N_WA1 + N_WA2) {
        int u = t - N_WA1;
        int o = u / 320, kv = u - o * 320, kk = kv / 32, c = kv - kk * 32;
        float s = (o < 50 && c < 25) ? w2[(o * 25 + c) * 10 + kk] : 0.f;
        wsh[H_WA2 + u] = __float2bfloat16(s);
    } else if (t < N_WA1 + N_WA2 + N_WA3) {
        int u = t - N_WA1 - N_WA2;
        int o = u / 640, kv = u - o * 640, kk = kv / 64, c = kv - kk * 64;
        float s = (o < 100 && c < 50) ? w3[(o * 50 + c) * 10 + kk] : 0.f;
        wsh[H_WA3 + u] = __float2bfloat16(s);
    } else if (t < N_WTOT) {
        int u = t - N_WA1 - N_WA2 - N_WA3;
        int o = u / 1280, kv = u - o * 1280, kk = kv / 128, c = kv - kk * 128;
        float s = (o < 200 && c < 100) ? w4[(o * 100 + c) * 10 + kk] : 0.f;
        wsh[H_WA4 + u] = __float2bfloat16(s);
    } else {
        int j = t - N_WTOT;
        if (j < 25) {
            float sc = g1[j] / sqrtf(v1[j] + 1e-5f);
            ws[F_S1 + j] = sc; ws[F_H1 + j] = b1[j] - m1[j] * sc;
        } else if (j >= 32 && j < 82) {
            int ch = j - 32;
            float sc = g2[ch] / sqrtf(v2[ch] + 1e-5f);
            ws[F_S2 + ch] = sc; ws[F_H2 + ch] = b2[ch] - m2[ch] * sc;
        } else if (j >= 96 && j < 196) {
            int ch = j - 96;
            float sc = g3[ch] / sqrtf(v3[ch] + 1e-5f);
            ws[F_S3 + ch] = sc; ws[F_H3 + ch] = b3[ch] - m3[ch] * sc;
        } else if (j >= 224 && j < 424) {
            int ch = j - 224;
            float sc = g4[ch] / sqrtf(v4[ch] + 1e-5f);
            ws[F_S4 + ch] = sc; ws[F_H4 + ch] = b4[ch] - m4[ch] * sc;
        } else if (j >= 448 && j < 473) {
            int o = j - 448;
            float s = 0.f;
            for (int i = 0; i < 25; ++i) {
                float cs = 0.f;
                for (int c = 0; c < 64; ++c) cs += cs_w[(o * 25 + i) * 64 + c];
                s += cs * ct_b[i];
            }
            ws[F_B1 + o] = s;
        }
    }
}

// ---------------- unified MFMA conv + BN + ELU + pool3 ----------------
// D[o][t] = sum_{c,kk} W[o][c][kk] * in[c][t+kk]; rows=o tiles of 16,
// cols = 16 consecutive t; K = 10*CINP, ordered (kk major, c minor).
// x staged in LDS transposed [t][c] bf16 with XOR swizzle; pool via eb buffer.
template<typename IT, typename OT, int CIN, int CINP, int COUT, int TINLEN,
         int TPOOL, int PT, int OSPLIT, int EBS, int ROWS, bool BIAS>
__global__ __launch_bounds__(256) void k_convmf(
    const IT* __restrict__ in, OT* __restrict__ outp,
    const __hip_bfloat16* __restrict__ Wa,
    const float* __restrict__ sv, const float* __restrict__ hv,
    const float* __restrict__ bv) {
    constexpr int K   = CINP * 10;
    constexpr int NS  = K / 32;
    constexpr int CB  = CINP / 32;
    constexpr int NOT = (COUT + 15) / 16;
    constexpr int NOTP = (NOT + OSPLIT - 1) / OSPLIT;
    constexpr int SWM = (CINP >= 64) ? 7 : 3;

    int bx = blockIdx.x, b = blockIdx.y;
    int tt = bx / OSPLIT, os = bx % OSPLIT;
    int p0 = tt * PT;
    int PTb = min(PT, TPOOL - p0);
    int t0 = 3 * p0;
    int otLo = os * NOTP;
    int otHi = min(NOT, otLo + NOTP);
    int NOTb = otHi - otLo;
    int Tval = 3 * PTb;
    int NCTb = (Tval + 15) / 16;

    __shared__ __hip_bfloat16 xb[ROWS * CINP];
    __shared__ float eb[COUT * EBS];

    // ---- stage input transposed [t][c] bf16, swizzled, zero-padded ----
    for (int e = threadIdx.x; e < ROWS * CINP; e += 256) {
        int r = e % ROWS, c = e / ROWS;
        int t = t0 + r;
        float v = 0.f;
        if (t < TINLEN && c < CIN)
            v = ldf(in + ((size_t)b * CIN + c) * TINLEN + t);
        xb[r * CINP + (c ^ ((r & SWM) * 8))] = __float2bfloat16(v);
    }
    __syncthreads();

    // ---- MFMA items: (otile, coltile) ----
    int lane = threadIdx.x & 63;
    int wid  = threadIdx.x >> 6;
    int lo = lane & 15, kg = lane >> 4;
    int items = NCTb * NOTb;
    for (int it = wid; it < items; it += 4) {
        int ct = it % NCTb;
        int ot = otLo + it / NCTb;
        const short8v* Ap = (const short8v*)(Wa + (size_t)(ot * 16 + lo) * K);
        f32x4 acc = {0.f, 0.f, 0.f, 0.f};
#pragma unroll
        for (int s = 0; s < NS; ++s) {
            int kk = s / CB, cb = s - kk * CB;
            int r = ct * 16 + lo + kk;
            int cs = (cb * 32 + kg * 8) ^ ((r & SWM) * 8);
            short8v bfr = *(const short8v*)&xb[r * CINP + cs];
            short8v afr = Ap[s * 4 + kg];
            acc = __builtin_amdgcn_mfma_f32_16x16x32_bf16(afr, bfr, acc, 0, 0, 0);
        }
        int tloc = ct * 16 + lo;
#pragma unroll
        for (int q = 0; q < 4; ++q) {
            int o2 = ot * 16 + kg * 4 + q;
            if (o2 < COUT) {
                float a = acc[q];
                if (BIAS) a += bv[o2];
                eb[o2 * EBS + tloc] = eluf(a * sv[o2] + hv[o2]);
            }
        }
    }
    __syncthreads();

    // ---- pooled max(3) + store ----
    int oLo = otLo * 16;
    int oHi = min(COUT, otHi * 16);
    int np = (oHi - oLo) * PTb;
    for (int i = threadIdx.x; i < np; i += 256) {
        int o = oLo + i / PTb, pl = i % PTb;
        const float* ep = eb + o * EBS + 3 * pl;
        float m = fmaxf(fmaxf(ep[0], ep[1]), ep[2]);
        stf(outp + ((size_t)b * COUT + o) * TPOOL + p0 + pl, m);
    }
}

// ---------------- K5: fc conv + per-sample MoE heads ----------------
__global__ __launch_bounds__(128) void k_heads(
    const float* __restrict__ p4,
    const float* __restrict__ fcw, const float* __restrict__ fcb,
    const int* __restrict__ cids,
    const float* __restrict__ hW1, const float* __restrict__ hb1,
    const float* __restrict__ hW2, const float* __restrict__ hb2,
    float* __restrict__ out) {
    __shared__ float red[4][128];
    __shared__ float fs[4];
    int b = blockIdx.x, j = threadIdx.x;

    float pa[4] = {0.f, 0.f, 0.f, 0.f};
    for (int c = j; c < 200; c += 128) {
        const float* pp = p4 + ((size_t)b * 200 + c) * 4;
        float v0 = pp[0], v1 = pp[1], v2 = pp[2], v3 = pp[3];
#pragma unroll
        for (int o = 0; o < 4; ++o) {
            const float* fw = fcw + (o * 200 + c) * 4;
            pa[o] += fw[0] * v0 + fw[1] * v1 + fw[2] * v2 + fw[3] * v3;
        }
    }
#pragma unroll
    for (int o = 0; o < 4; ++o) red[o][j] = pa[o];
    __syncthreads();
    for (int s = 64; s > 0; s >>= 1) {
        if (j < s) {
#pragma unroll
            for (int o = 0; o < 4; ++o) red[o][j] += red[o][j + s];
        }
        __syncthreads();
    }
    if (j < 4) fs[j] = red[j][0] + fcb[j];
    __syncthreads();

    int cid = cids[b];
    float hvv = hb1[cid * 128 + j];
#pragma unroll
    for (int f = 0; f < 4; ++f) hvv += fs[f] * hW1[(cid * 4 + f) * 128 + j];
    hvv = fmaxf(hvv, 0.f);
#pragma unroll
    for (int o = 0; o < 4; ++o) red[o][j] = hvv * hW2[(cid * 128 + j) * 4 + o];
    __syncthreads();
    for (int s = 64; s > 0; s >>= 1) {
        if (j < s) {
#pragma unroll
            for (int o = 0; o < 4; ++o) red[o][j] += red[o][j + s];
        }
        __syncthreads();
    }
    if (j < 4) out[b * 4 + j] = red[j][0] + hb2[cid * 4 + j];
}

// ---------------- launch ----------------
extern "C" void kernel_launch(void* const* d_in, const int* in_sizes, int n_in,
                              void* d_out, int out_size, void* d_ws, size_t ws_size,
                              hipStream_t stream) {
    (void)in_sizes; (void)n_in; (void)out_size; (void)ws_size;
    const float* x    = (const float*)d_in[0];
    const int*   cid  = (const int*)d_in[1];
    const float* ctw  = (const float*)d_in[2];
    const float* ctb  = (const float*)d_in[3];
    const float* csw  = (const float*)d_in[4];
    const float* g1 = (const float*)d_in[5],  *b1 = (const float*)d_in[6];
    const float* m1 = (const float*)d_in[7],  *v1 = (const float*)d_in[8];
    const float* w2 = (const float*)d_in[9];
    const float* g2 = (const float*)d_in[10], *b2 = (const float*)d_in[11];
    const float* m2 = (const float*)d_in[12], *v2 = (const float*)d_in[13];
    const float* w3 = (const float*)d_in[14];
    const float* g3 = (const float*)d_in[15], *b3 = (const float*)d_in[16];
    const float* m3 = (const float*)d_in[17], *v3 = (const float*)d_in[18];
    const float* w4 = (const float*)d_in[19];
    const float* g4 = (const float*)d_in[20], *b4 = (const float*)d_in[21];
    const float* m4 = (const float*)d_in[22], *v4 = (const float*)d_in[23];
    const float* fcw = (const float*)d_in[24], *fcb = (const float*)d_in[25];
    const float* hW1 = (const float*)d_in[26], *hb1 = (const float*)d_in[27];
    const float* hW2 = (const float*)d_in[28], *hb2 = (const float*)d_in[29];
    float* ws  = (float*)d_ws;
    __hip_bfloat16* wsh = (__hip_bfloat16*)d_ws;
    float* out = (float*)d_out;

    k_pre2<<<dim3((N_WTOT + 512 + 255) / 256), dim3(256), 0, stream>>>(
        ctw, ctb, csw, g1, b1, m1, v1, w2, g2, b2, m2, v2,
        w3, g3, b3, m3, v3, w4, g4, b4, m4, v4, ws);

    // L1: 64ch fused conv, 750 -> pool 247
    k_convmf<float, __hip_bfloat16, 64, 64, 25, 750, 247, 64, 1, 196, 208, true>
        <<<dim3(4, 128), dim3(256), 0, stream>>>(
            x, wsh + H_P1, wsh + H_WA1, ws + F_S1, ws + F_H1, ws + F_B1);
    // L2: 25->50, 247 -> pool 79
    k_convmf<__hip_bfloat16, __hip_bfloat16, 25, 32, 50, 247, 79, 64, 1, 196, 208, false>
        <<<dim3(2, 128), dim3(256), 0, stream>>>(
            wsh + H_P1, wsh + H_P2, wsh + H_WA2, ws + F_S2, ws + F_H2, ws + F_B1);
    // L3: 50->100, 79 -> pool 23
    k_convmf<__hip_bfloat16, __hip_bfloat16, 50, 64, 100, 79, 23, 23, 2, 84, 96, false>
        <<<dim3(2, 128), dim3(256), 0, stream>>>(
            wsh + H_P2, wsh + H_P3, wsh + H_WA3, ws + F_S3, ws + F_H3, ws + F_B1);
    // L4: 100->200, 23 -> pool 4 (fp32 out for heads)
    k_convmf<__hip_bfloat16, float, 100, 128, 200, 23, 4, 4, 2, 16, 32, false>
        <<<dim3(2, 128), dim3(256), 0, stream>>>(
            wsh + H_P3, ws + F_P4, wsh + H_WA4, ws + F_S4, ws + F_H4, ws + F_B1);

    k_heads<<<dim3(128), dim3(128), 0, stream>>>(ws + F_P4, fcw, fcb, cid,
                                                 hW1, hb1, hW2, hb2, out);
}

// Round 4
// 94.566 us; speedup vs baseline: 3.0374x; 1.7572x over previous
//
#include <hip/hip_runtime.h>
#include <hip/hip_bf16.h>
#include <math.h>

typedef __attribute__((ext_vector_type(8))) short short8v;
typedef __attribute__((ext_vector_type(4))) float f32x4;

// ---------------- ws layout ----------------
// float region (offsets in floats):
#define F_S1 0
#define F_H1 32
#define F_S2 64
#define F_H2 128
#define F_S3 192
#define F_H3 320
#define F_S4 448
#define F_H4 704
#define F_B1 960
#define F_P4 1024                       // 128*200*4 floats
#define F_END (1024 + 128*200*4)
// bf16 region (offsets in bf16 units):
#define H_BASE (F_END * 2)
#define H_P1  H_BASE                    // 128*25*248  (stride 248, 247 valid)
#define H_P2  (H_P1 + 128*25*248)       // 128*50*80   (stride 80, 79 valid)
#define H_P3  (H_P2 + 128*50*80)        // 128*100*24  (stride 24, 23 valid)
#define H_WA1 (H_P3 + 128*100*24)       // 32*640
#define H_WA2 (H_WA1 + 32*640)          // 64*320
#define H_WA3 (H_WA2 + 64*320)          // 112*640
#define H_WA4 (H_WA3 + 112*640)         // 208*1280

__device__ __forceinline__ float eluf(float v) {
    return v > 0.f ? v : (expf(v) - 1.f);
}
__device__ __forceinline__ float ldf(const float* p) { return *p; }
__device__ __forceinline__ float ldf(const __hip_bfloat16* p) { return __bfloat162float(*p); }
__device__ __forceinline__ void stf(float* p, float v) { *p = v; }
__device__ __forceinline__ void stf(__hip_bfloat16* p, float v) { *p = __float2bfloat16(v); }

__device__ __forceinline__ void ld4(const float* p, float* v) {
    float2 a = *(const float2*)p, c = *(const float2*)(p + 2);
    v[0] = a.x; v[1] = a.y; v[2] = c.x; v[3] = c.y;
}
__device__ __forceinline__ void ld4(const __hip_bfloat16* p, float* v) {
    uint2 u = *(const uint2*)p;
    v[0] = __uint_as_float((u.x & 0xffffu) << 16);
    v[1] = __uint_as_float(u.x & 0xffff0000u);
    v[2] = __uint_as_float((u.y & 0xffffu) << 16);
    v[3] = __uint_as_float(u.y & 0xffff0000u);
}

// ---------------- K0: precompute bf16 k-major weights + BN affines ----------------
#define N_WA1 (32*640)
#define N_WA2 (64*320)
#define N_WA3 (112*640)
#define N_WA4 (208*1280)
#define N_WTOT (N_WA1 + N_WA2 + N_WA3 + N_WA4)

__global__ __launch_bounds__(256) void k_pre2(
    const float* __restrict__ ct_w, const float* __restrict__ ct_b,
    const float* __restrict__ cs_w,
    const float* __restrict__ g1, const float* __restrict__ b1,
    const float* __restrict__ m1, const float* __restrict__ v1,
    const float* __restrict__ w2,
    const float* __restrict__ g2, const float* __restrict__ b2,
    const float* __restrict__ m2, const float* __restrict__ v2,
    const float* __restrict__ w3,
    const float* __restrict__ g3, const float* __restrict__ b3,
    const float* __restrict__ m3, const float* __restrict__ v3,
    const float* __restrict__ w4,
    const float* __restrict__ g4, const float* __restrict__ b4,
    const float* __restrict__ m4, const float* __restrict__ v4,
    float* __restrict__ ws) {
    __hip_bfloat16* wsh = (__hip_bfloat16*)ws;
    int t = blockIdx.x * 256 + threadIdx.x;
    if (t < N_WA1) {
        int o = t / 640, kv = t - o * 640, kk = kv / 64, c = kv - kk * 64;
        float s = 0.f;
        if (o < 25)
            for (int i = 0; i < 25; ++i)
                s += cs_w[(o * 25 + i) * 64 + c] * ct_w[i * 10 + kk];
        wsh[H_WA1 + t] = __float2bfloat16(s);
    } else if (t < N_WA1 + N_WA2) {
        int u = t - N_WA1;
        int o = u / 320, kv = u - o * 320, kk = kv / 32, c = kv - kk * 32;
        float s = (o < 50 && c < 25) ? w2[(o * 25 + c) * 10 + kk] : 0.f;
        wsh[H_WA2 + u] = __float2bfloat16(s);
    } else if (t < N_WA1 + N_WA2 + N_WA3) {
        int u = t - N_WA1 - N_WA2;
        int o = u / 640, kv = u - o * 640, kk = kv / 64, c = kv - kk * 64;
        float s = (o < 100 && c < 50) ? w3[(o * 50 + c) * 10 + kk] : 0.f;
        wsh[H_WA3 + u] = __float2bfloat16(s);
    } else if (t < N_WTOT) {
        int u = t - N_WA1 - N_WA2 - N_WA3;
        int o = u / 1280, kv = u - o * 1280, kk = kv / 128, c = kv - kk * 128;
        float s = (o < 200 && c < 100) ? w4[(o * 100 + c) * 10 + kk] : 0.f;
        wsh[H_WA4 + u] = __float2bfloat16(s);
    } else {
        int j = t - N_WTOT;
        if (j < 25) {
            float sc = g1[j] / sqrtf(v1[j] + 1e-5f);
            ws[F_S1 + j] = sc; ws[F_H1 + j] = b1[j] - m1[j] * sc;
        } else if (j >= 32 && j < 82) {
            int ch = j - 32;
            float sc = g2[ch] / sqrtf(v2[ch] + 1e-5f);
            ws[F_S2 + ch] = sc; ws[F_H2 + ch] = b2[ch] - m2[ch] * sc;
        } else if (j >= 96 && j < 196) {
            int ch = j - 96;
            float sc = g3[ch] / sqrtf(v3[ch] + 1e-5f);
            ws[F_S3 + ch] = sc; ws[F_H3 + ch] = b3[ch] - m3[ch] * sc;
        } else if (j >= 224 && j < 424) {
            int ch = j - 224;
            float sc = g4[ch] / sqrtf(v4[ch] + 1e-5f);
            ws[F_S4 + ch] = sc; ws[F_H4 + ch] = b4[ch] - m4[ch] * sc;
        } else if (j >= 448 && j < 473) {
            int o = j - 448;
            float s = 0.f;
            for (int i = 0; i < 25; ++i) {
                float cs = 0.f;
                for (int c = 0; c < 64; ++c) cs += cs_w[(o * 25 + i) * 64 + c];
                s += cs * ct_b[i];
            }
            ws[F_B1 + o] = s;
        }
    }
}

// ---------------- unified MFMA conv + BN + ELU + pool3 ----------------
// A row layout: W[o][k], k = kk*CINP + c (k-major, matches B construction).
// B from LDS xb[t][c] bf16, XOR-swizzled (granularity 8 elems = 16B).
// s-loop outer: one global A-frag reused across CTW col-tiles (pipelines).
template<typename IT, typename OT, int CIN, int CINP, int COUT,
         int TINLEN, int TSIN, int TPOOL, int TSOUT,
         int PT, int OSPLIT, int NCT, int CSPLIT, int ROWS, bool BIAS>
__global__ __launch_bounds__(256) void k_convmf(
    const IT* __restrict__ in, OT* __restrict__ outp,
    const __hip_bfloat16* __restrict__ Wa,
    const float* __restrict__ sv, const float* __restrict__ hv,
    const float* __restrict__ bv) {
    constexpr int K    = CINP * 10;
    constexpr int NS   = K / 32;
    constexpr int CB   = CINP / 32;
    constexpr int NOT  = (COUT + 15) / 16;
    constexpr int NOTP = (NOT + OSPLIT - 1) / OSPLIT;
    constexpr int SWM  = (CINP >= 64) ? 7 : 3;
    constexpr int EBS  = NCT * 16;
    constexpr int CTW  = NCT / CSPLIT;
    constexpr int CHR  = ROWS / 4;

    int bx = blockIdx.x, b = blockIdx.y;
    int tt = bx / OSPLIT, os = bx % OSPLIT;
    int p0 = tt * PT;
    int PTb = min(PT, TPOOL - p0);
    int t0 = 3 * p0;
    int otLo = os * NOTP;
    int NOTb = min(NOT - otLo, NOTP);

    __shared__ __hip_bfloat16 xb[ROWS * CINP];
    __shared__ float eb[NOTP * 16 * EBS];

    // ---- stage input transposed [t][c] bf16, swizzled, zero-padded ----
    for (int f = threadIdx.x; f < CIN * CHR; f += 256) {
        int c = f / CHR, j = f - c * CHR;
        int t = t0 + 4 * j;
        const IT* src = in + ((size_t)b * CIN + c) * TSIN + t;
        float v[4];
        if (t + 3 < TINLEN) {
            ld4(src, v);
        } else {
#pragma unroll
            for (int e = 0; e < 4; ++e)
                v[e] = (t + e < TINLEN) ? ldf(src + e) : 0.f;
        }
#pragma unroll
        for (int e = 0; e < 4; ++e) {
            int r = 4 * j + e;
            xb[r * CINP + (c ^ (8 * (r & SWM)))] = __float2bfloat16(v[e]);
        }
    }
    if constexpr (CINP > CIN) {
        for (int f = threadIdx.x; f < (CINP - CIN) * ROWS; f += 256) {
            int c = CIN + f / ROWS, r = f % ROWS;
            xb[r * CINP + (c ^ (8 * (r & SWM)))] = __float2bfloat16(0.f);
        }
    }
    __syncthreads();

    // ---- MFMA: wave -> (ot, ct-group); s outer, ct inner ----
    int lane = threadIdx.x & 63, wid = threadIdx.x >> 6;
    int lo = lane & 15, kg = lane >> 4;
    int ctg = wid % CSPLIT;
    for (int oi = wid / CSPLIT; oi < NOTb; oi += 4 / CSPLIT) {
        int ot = otLo + oi;
        const short8v* Ap = (const short8v*)(Wa + (size_t)(ot * 16 + lo) * K);
        f32x4 acc[CTW];
#pragma unroll
        for (int q = 0; q < CTW; ++q) acc[q] = (f32x4){0.f, 0.f, 0.f, 0.f};
#pragma unroll
        for (int s = 0; s < NS; ++s) {
            short8v afr = Ap[s * 4 + kg];
            int kk = s / CB, cb = s - kk * CB;
#pragma unroll
            for (int q = 0; q < CTW; ++q) {
                int ct = ctg * CTW + q;
                int r = ct * 16 + lo + kk;
                int cs = (cb * 32 + kg * 8) ^ (8 * (r & SWM));
                short8v bfr = *(const short8v*)&xb[r * CINP + cs];
                acc[q] = __builtin_amdgcn_mfma_f32_16x16x32_bf16(afr, bfr, acc[q], 0, 0, 0);
            }
        }
#pragma unroll
        for (int q = 0; q < CTW; ++q) {
            int tloc = (ctg * CTW + q) * 16 + lo;
#pragma unroll
            for (int e = 0; e < 4; ++e) {
                int o2 = ot * 16 + kg * 4 + e;
                if (o2 < COUT) {
                    float a = acc[q][e];
                    if (BIAS) a += bv[o2];
                    eb[(o2 - otLo * 16) * EBS + tloc] = eluf(a * sv[o2] + hv[o2]);
                }
            }
        }
    }
    __syncthreads();

    // ---- pooled max(3) + store ----
    int oLo = otLo * 16;
    int nO = min(COUT, (otLo + NOTb) * 16) - oLo;
    for (int i = threadIdx.x; i < nO * PT; i += 256) {
        int o = oLo + i / PT, pl = i % PT;
        if (pl < PTb) {
            const float* ep = eb + (o - oLo) * EBS + 3 * pl;
            float m = fmaxf(fmaxf(ep[0], ep[1]), ep[2]);
            stf(outp + ((size_t)b * COUT + o) * TSOUT + p0 + pl, m);
        }
    }
}

// ---------------- K5: fc conv + per-sample MoE heads ----------------
__global__ __launch_bounds__(128) void k_heads(
    const float* __restrict__ p4,
    const float* __restrict__ fcw, const float* __restrict__ fcb,
    const int* __restrict__ cids,
    const float* __restrict__ hW1, const float* __restrict__ hb1,
    const float* __restrict__ hW2, const float* __restrict__ hb2,
    float* __restrict__ out) {
    __shared__ float red[4][128];
    __shared__ float fs[4];
    int b = blockIdx.x, j = threadIdx.x;

    float pa[4] = {0.f, 0.f, 0.f, 0.f};
    for (int c = j; c < 200; c += 128) {
        const float* pp = p4 + ((size_t)b * 200 + c) * 4;
        float v0 = pp[0], v1 = pp[1], v2 = pp[2], v3 = pp[3];
#pragma unroll
        for (int o = 0; o < 4; ++o) {
            const float* fw = fcw + (o * 200 + c) * 4;
            pa[o] += fw[0] * v0 + fw[1] * v1 + fw[2] * v2 + fw[3] * v3;
        }
    }
#pragma unroll
    for (int o = 0; o < 4; ++o) red[o][j] = pa[o];
    __syncthreads();
    for (int s = 64; s > 0; s >>= 1) {
        if (j < s) {
#pragma unroll
            for (int o = 0; o < 4; ++o) red[o][j] += red[o][j + s];
        }
        __syncthreads();
    }
    if (j < 4) fs[j] = red[j][0] + fcb[j];
    __syncthreads();

    int cid = cids[b];
    float hvv = hb1[cid * 128 + j];
#pragma unroll
    for (int f = 0; f < 4; ++f) hvv += fs[f] * hW1[(cid * 4 + f) * 128 + j];
    hvv = fmaxf(hvv, 0.f);
#pragma unroll
    for (int o = 0; o < 4; ++o) red[o][j] = hvv * hW2[(cid * 128 + j) * 4 + o];
    __syncthreads();
    for (int s = 64; s > 0; s >>= 1) {
        if (j < s) {
#pragma unroll
            for (int o = 0; o < 4; ++o) red[o][j] += red[o][j + s];
        }
        __syncthreads();
    }
    if (j < 4) out[b * 4 + j] = red[j][0] + hb2[cid * 4 + j];
}

// ---------------- launch ----------------
extern "C" void kernel_launch(void* const* d_in, const int* in_sizes, int n_in,
                              void* d_out, int out_size, void* d_ws, size_t ws_size,
                              hipStream_t stream) {
    (void)in_sizes; (void)n_in; (void)out_size; (void)ws_size;
    const float* x    = (const float*)d_in[0];
    const int*   cid  = (const int*)d_in[1];
    const float* ctw  = (const float*)d_in[2];
    const float* ctb  = (const float*)d_in[3];
    const float* csw  = (const float*)d_in[4];
    const float* g1 = (const float*)d_in[5],  *b1 = (const float*)d_in[6];
    const float* m1 = (const float*)d_in[7],  *v1 = (const float*)d_in[8];
    const float* w2 = (const float*)d_in[9];
    const float* g2 = (const float*)d_in[10], *b2 = (const float*)d_in[11];
    const float* m2 = (const float*)d_in[12], *v2 = (const float*)d_in[13];
    const float* w3 = (const float*)d_in[14];
    const float* g3 = (const float*)d_in[15], *b3 = (const float*)d_in[16];
    const float* m3 = (const float*)d_in[17], *v3 = (const float*)d_in[18];
    const float* w4 = (const float*)d_in[19];
    const float* g4 = (const float*)d_in[20], *b4 = (const float*)d_in[21];
    const float* m4 = (const float*)d_in[22], *v4 = (const float*)d_in[23];
    const float* fcw = (const float*)d_in[24], *fcb = (const float*)d_in[25];
    const float* hW1 = (const float*)d_in[26], *hb1 = (const float*)d_in[27];
    const float* hW2 = (const float*)d_in[28], *hb2 = (const float*)d_in[29];
    float* ws  = (float*)d_ws;
    __hip_bfloat16* wsh = (__hip_bfloat16*)d_ws;
    float* out = (float*)d_out;

    k_pre2<<<dim3((N_WTOT + 512 + 255) / 256), dim3(256), 0, stream>>>(
        ctw, ctb, csw, g1, b1, m1, v1, w2, g2, b2, m2, v2,
        w3, g3, b3, m3, v3, w4, g4, b4, m4, v4, ws);

    // L1: 64ch fused conv, 750 -> pool 247. 8 t-tiles, grid 1024.
    k_convmf<float, __hip_bfloat16, 64, 64, 25, 750, 750, 247, 248,
             32, 1, 6, 2, 112, true>
        <<<dim3(8, 128), dim3(256), 0, stream>>>(
            x, wsh + H_P1, wsh + H_WA1, ws + F_S1, ws + F_H1, ws + F_B1);
    // L2: 25->50, 247 -> pool 79. 4 t-tiles, grid 512.
    k_convmf<__hip_bfloat16, __hip_bfloat16, 25, 32, 50, 247, 248, 79, 80,
             20, 1, 4, 1, 80, false>
        <<<dim3(4, 128), dim3(256), 0, stream>>>(
            wsh + H_P1, wsh + H_P2, wsh + H_WA2, ws + F_S2, ws + F_H2, ws + F_B1);
    // L3: 50->100, 79 -> pool 23. 2 t-tiles x 2 o-splits, grid 512.
    k_convmf<__hip_bfloat16, __hip_bfloat16, 50, 64, 100, 79, 80, 23, 24,
             12, 2, 3, 1, 64, false>
        <<<dim3(4, 128), dim3(256), 0, stream>>>(
            wsh + H_P2, wsh + H_P3, wsh + H_WA3, ws + F_S3, ws + F_H3, ws + F_B1);
    // L4: 100->200, 23 -> pool 4 (fp32 out). 4 o-splits, grid 512.
    k_convmf<__hip_bfloat16, float, 100, 128, 200, 23, 24, 4, 4,
             4, 4, 1, 1, 32, false>
        <<<dim3(4, 128), dim3(256), 0, stream>>>(
            wsh + H_P3, ws + F_P4, wsh + H_WA4, ws + F_S4, ws + F_H4, ws + F_B1);

    k_heads<<<dim3(128), dim3(128), 0, stream>>>(ws + F_P4, fcw, fcb, cid,
                                                 hW1, hb1, hW2, hb2, out);
}